// Round 1
// 1878.982 us; speedup vs baseline: 1.1684x; 1.1684x over previous
//
#include <hip/hip_runtime.h>

// Problem constants
constexpr int Bc = 32, Nc = 2048, Fc = 64, Tc = 24;

// ---------- helpers ----------
__device__ __forceinline__ unsigned short f2bf(float f) {
  unsigned u = __float_as_uint(f);
  u += 0x7fffu + ((u >> 16) & 1u);   // round-to-nearest-even
  return (unsigned short)(u >> 16);
}

#define AS1(p) ((const __attribute__((address_space(1))) unsigned int*)(p))
#define AS3(p) ((__attribute__((address_space(3))) unsigned int*)(p))

typedef __attribute__((ext_vector_type(8))) short bfrag;   // 8 bf16 (4 VGPRs)
typedef __attribute__((ext_vector_type(4))) float ffrag;   // 4 fp32 acc

// ---------- Kernel A: x -> lhs[b,n,t], rhsT[b,m,t] ----------
__global__ __launch_bounds__(256) void kA(const float* __restrict__ x,
                                          const float* __restrict__ W1,
                                          const float* __restrict__ W2,
                                          const float* __restrict__ W3,
                                          float* __restrict__ lhs,
                                          float* __restrict__ rhsT) {
  __shared__ float W2s[Fc * Tc];      // 64x24
  __shared__ float xs[4][Fc][26];     // pad 24->26: breaks stride-24 bank aliasing
  __shared__ float tmp[4][Fc];
  const int tid = threadIdx.x;
  for (int i = tid; i < Fc * Tc; i += 256) W2s[i] = W2[i];
  const int wave = tid >> 6, lane = tid & 63;
  const size_t pair = (size_t)blockIdx.x * 4 + wave;   // pair = b*N + n
  const float* xp = x + pair * (size_t)(Fc * Tc);
#pragma unroll
  for (int s = 0; s < 12; ++s) {
    int f2 = lane + 64 * s;           // 0..767
    int row = f2 / 12, c2 = (f2 % 12) * 2;
    float2 v = *(const float2*)(xp + (size_t)f2 * 2);
    xs[wave][row][c2] = v.x;
    xs[wave][row][c2 + 1] = v.y;
  }
  __syncthreads();
  {
    const int f = lane;
    float acc = 0.f;
#pragma unroll
    for (int t = 0; t < Tc; ++t) acc += xs[wave][f][t] * W1[t];
    tmp[wave][f] = acc;
  }
  __syncthreads();
  if (lane < 48) {
    const int t = lane >> 1, h = lane & 1;
    const int f0 = h * 32;
    float lacc = 0.f, racc = 0.f;
#pragma unroll
    for (int i = 0; i < 32; ++i) {
      int f = f0 + i;
      lacc += tmp[wave][f] * W2s[f * Tc + t];
      racc += W3[f] * xs[wave][f][t];
    }
    lacc += __shfl_xor(lacc, 1);
    racc += __shfl_xor(racc, 1);
    if (h == 0) {
      lhs[pair * Tc + t] = lacc;
      rhsT[pair * Tc + t] = racc;
    }
  }
}

// ---------- Kernel V: Vs fp32 -> bf16 ----------
__global__ __launch_bounds__(256) void kVs(const float* __restrict__ Vs,
                                           unsigned short* __restrict__ Vb) {
  size_t i = ((size_t)blockIdx.x * 256 + threadIdx.x) * 4;
  float4 v = *(const float4*)(Vs + i);
  ushort4 o;
  o.x = f2bf(v.x); o.y = f2bf(v.y); o.z = f2bf(v.z); o.w = f2bf(v.w);
  *(ushort4*)(Vb + i) = o;
}

// ---------- Kernel P: sigT[b][m][k] = sigmoid(lhs[b,k,:].rhsT[b,m,:] + bs[k,m]) ----------
__global__ __launch_bounds__(256) void kP(const float* __restrict__ lhs,
                                          const float* __restrict__ rhsT,
                                          const float* __restrict__ bsr,
                                          unsigned short* __restrict__ sigT) {
  __shared__ float Lt[Tc][132];
  __shared__ float Rt[Tc][132];
  const int b = blockIdx.z;
  const int i0 = blockIdx.y * 128;
  const int j0 = blockIdx.x * 128;
  const int tid = threadIdx.x;
  const float* lp = lhs + ((size_t)b * Nc + i0) * Tc;
  const float* rp = rhsT + ((size_t)b * Nc + j0) * Tc;
#pragma unroll
  for (int s = 0; s < 6; ++s) {
    int f2 = tid + 256 * s;                 // 0..1535
    int row = f2 / 12, c2 = (f2 % 12) * 2;
    float2 v = *(const float2*)(lp + (size_t)row * Tc + c2);
    Lt[c2][row] = v.x; Lt[c2 + 1][row] = v.y;
    float2 w = *(const float2*)(rp + (size_t)row * Tc + c2);
    Rt[c2][row] = w.x; Rt[c2 + 1][row] = w.y;
  }
  __syncthreads();
  const int tx = tid & 15, ty = tid >> 4;
  const int ri = ty * 8, cj = tx * 8;
  float acc[8][8];
#pragma unroll
  for (int a = 0; a < 8; ++a) {   // init with bs tile
    const float* bp = bsr + (size_t)(i0 + ri + a) * Nc + j0 + cj;
    float4 b0 = *(const float4*)bp;
    float4 b1 = *(const float4*)(bp + 4);
    acc[a][0] = b0.x; acc[a][1] = b0.y; acc[a][2] = b0.z; acc[a][3] = b0.w;
    acc[a][4] = b1.x; acc[a][5] = b1.y; acc[a][6] = b1.z; acc[a][7] = b1.w;
  }
#pragma unroll
  for (int t = 0; t < Tc; ++t) {
    float la[8], ra[8];
    *(float4*)&la[0] = *(const float4*)&Lt[t][ri];
    *(float4*)&la[4] = *(const float4*)&Lt[t][ri + 4];
    *(float4*)&ra[0] = *(const float4*)&Rt[t][cj];
    *(float4*)&ra[4] = *(const float4*)&Rt[t][cj + 4];
#pragma unroll
    for (int a = 0; a < 8; ++a)
#pragma unroll
      for (int c = 0; c < 8; ++c) acc[a][c] += la[a] * ra[c];
  }
#pragma unroll
  for (int c = 0; c < 8; ++c) {
    unsigned short o[8];
#pragma unroll
    for (int a = 0; a < 8; ++a) {
      float e = __expf(-acc[a][c]);
      o[a] = f2bf(__fdividef(1.0f, 1.0f + e));
    }
    uint4 pk;
    pk.x = (unsigned)o[0] | ((unsigned)o[1] << 16);
    pk.y = (unsigned)o[2] | ((unsigned)o[3] << 16);
    pk.z = (unsigned)o[4] | ((unsigned)o[5] << 16);
    pk.w = (unsigned)o[6] | ((unsigned)o[7] << 16);
    *(uint4*)(sigT + ((size_t)b * Nc + j0 + cj + c) * Nc + i0 + ri) = pk;
  }
}

// ---------- Kernel G: S[b] = Vs_bf16 (N,N) @ sig_bf16[b] (N,N), fp32 out ----------
// 256x256 tile, BK=64, 8 waves, 8-phase schedule (T1+T2+T3+T4+T5):
//  - LDS 128 KiB: As/Bs [2 dbuf][2 half][128 rows x 64 cols bf16], st_16x32 swizzle
//    (linear global_load_lds dest + inverse-swizzled global source + swizzled ds_read)
//  - per phase: ds_read subtile || stage 1 half-tile -> barrier -> lgkmcnt(0)
//    -> setprio(1) 16 MFMA setprio(0) -> barrier
//  - counted vmcnt(6) once per K-tile (3 half-tiles in flight); never 0 in main loop.
// Consumption (A-half,B-half) order per tile: (0,0),(0,1),(1,1),(1,0); stage stream per
// tile t: [B0(t+1)@ph0, A0(t+2)@ph1, B1(t+2)@ph2, A1(t+2)@ph3] -> every LDS half is
// last-read one full barrier-phase before its overwrite is issued (race-free).
__global__ __launch_bounds__(512, 2) void kG(const unsigned short* __restrict__ A,
                                             const unsigned short* __restrict__ Bm,
                                             float* __restrict__ S) {
  __shared__ unsigned short As[2][2][8192];   // [buf][M-half][128x64]
  __shared__ unsigned short Bs[2][2][8192];   // [buf][N-half][128x64]
  const int b = blockIdx.y;
  const int bid = blockIdx.x;
  const int swz = (bid & 7) * 8 + (bid >> 3);   // XCD swizzle, bijective (64 % 8 == 0)
  const int n0 = (swz >> 3) << 8;
  const int m0 = (swz & 7) << 8;
  const int tid = threadIdx.x;
  const int wid = tid >> 6, lane = tid & 63;
  const int wm = wid >> 2, wn = wid & 3;        // 2 x 4 waves
  const int quad = lane >> 4, l16 = lane & 15;
  const unsigned short* Bg = Bm + (size_t)b * Nc * Nc;

  // staging source offsets: LDS dest is linear (base + lane*16); global source is
  // the inverse-swizzled address so that swizzled ds_read returns correct data.
  int srow[2], scol[2], sbase[2];
#pragma unroll
  for (int c = 0; c < 2; ++c) {
    const int d = c * 8192 + (wid << 10) + (lane << 4);   // dest byte in 16 KiB half
    const int q = d ^ (((d >> 9) & 1) << 5);              // st_16x32 involution
    srow[c] = q >> 7;            // logical row (0..127)
    scol[c] = (q & 127) >> 1;    // logical col element (0..63)
    sbase[c] = (c * 8192 + (wid << 10)) >> 1;             // wave-uniform LDS short idx
  }

#define STAGE(arr, bufb, half, gb, ro, k0)                                         \
  do {                                                                             \
    _Pragma("unroll")                                                              \
    for (int c = 0; c < 2; ++c)                                                    \
      __builtin_amdgcn_global_load_lds(                                            \
          AS1(gb + (size_t)((ro) + srow[c]) * Nc + (k0) + scol[c]),                \
          AS3(&arr[bufb][half][0] + sbase[c]), 16, 0, 0);                          \
  } while (0)

  ffrag acc[2][4][2][2];
#pragma unroll
  for (int qm = 0; qm < 2; ++qm)
#pragma unroll
    for (int mi = 0; mi < 4; ++mi)
#pragma unroll
      for (int qn = 0; qn < 2; ++qn)
#pragma unroll
        for (int ni = 0; ni < 2; ++ni) acc[qm][mi][qn][ni] = (ffrag){0.f, 0.f, 0.f, 0.f};

  bfrag af[4][2], bfr[2][2];

#define LDA(qm, bufb)                                                              \
  do {                                                                             \
    _Pragma("unroll")                                                              \
    for (int mi = 0; mi < 4; ++mi)                                                 \
      _Pragma("unroll")                                                            \
      for (int ks = 0; ks < 2; ++ks) {                                             \
        const int lin = (wm * 64 + mi * 16 + l16) * 128 + ks * 64 + quad * 16;     \
        const int ph = lin ^ (((lin >> 9) & 1) << 5);                              \
        af[mi][ks] = *(const bfrag*)((const char*)&As[bufb][qm][0] + ph);          \
      }                                                                            \
  } while (0)

#define LDB(qn, bufb)                                                              \
  do {                                                                             \
    _Pragma("unroll")                                                              \
    for (int ni = 0; ni < 2; ++ni)                                                 \
      _Pragma("unroll")                                                            \
      for (int ks = 0; ks < 2; ++ks) {                                             \
        const int lin = (wn * 32 + ni * 16 + l16) * 128 + ks * 64 + quad * 16;     \
        const int ph = lin ^ (((lin >> 9) & 1) << 5);                              \
        bfr[ni][ks] = *(const bfrag*)((const char*)&Bs[bufb][qn][0] + ph);         \
      }                                                                            \
  } while (0)

#define MM(qm, qn)                                                                 \
  do {                                                                             \
    __builtin_amdgcn_s_setprio(1);                                                 \
    _Pragma("unroll")                                                              \
    for (int mi = 0; mi < 4; ++mi)                                                 \
      _Pragma("unroll")                                                            \
      for (int ni = 0; ni < 2; ++ni)                                               \
        _Pragma("unroll")                                                          \
        for (int ks = 0; ks < 2; ++ks)                                             \
          acc[qm][mi][qn][ni] = __builtin_amdgcn_mfma_f32_16x16x32_bf16(           \
              af[mi][ks], bfr[ni][ks], acc[qm][mi][qn][ni], 0, 0, 0);              \
    __builtin_amdgcn_s_setprio(0);                                                 \
  } while (0)

#define TILE(BUF, OT, T, DO_S1, DO_S2, ENDW)                                       \
  do {                                                                             \
    const int k1 = ((T) + 1) << 6, k2 = ((T) + 2) << 6;                            \
    /* phase 0: quadrant (0,0) */                                                  \
    LDA(0, BUF); LDB(0, BUF);                                                      \
    if (DO_S1) STAGE(Bs, OT, 0, Bg, m0, k1);                                       \
    asm volatile("s_waitcnt lgkmcnt(8)");                                          \
    __builtin_amdgcn_s_barrier();                                                  \
    asm volatile("s_waitcnt lgkmcnt(0)");                                          \
    MM(0, 0);                                                                      \
    __builtin_amdgcn_s_barrier();                                                  \
    /* phase 1: quadrant (0,1) — A-frags reused */                                 \
    LDB(1, BUF);                                                                   \
    if (DO_S2) STAGE(As, BUF, 0, A, n0, k2);                                       \
    __builtin_amdgcn_s_barrier();                                                  \
    asm volatile("s_waitcnt lgkmcnt(0)");                                          \
    MM(0, 1);                                                                      \
    __builtin_amdgcn_s_barrier();                                                  \
    /* phase 2: quadrant (1,1) — B-frags reused */                                 \
    LDA(1, BUF);                                                                   \
    if (DO_S2) STAGE(Bs, BUF, 1, Bg, m0 + 128, k2);                                \
    __builtin_amdgcn_s_barrier();                                                  \
    asm volatile("s_waitcnt lgkmcnt(0)");                                          \
    MM(1, 1);                                                                      \
    __builtin_amdgcn_s_barrier();                                                  \
    /* phase 3: quadrant (1,0) */                                                  \
    LDB(0, BUF);                                                                   \
    if (DO_S2) STAGE(As, BUF, 1, A, n0 + 128, k2);                                 \
    __builtin_amdgcn_s_barrier();                                                  \
    asm volatile("s_waitcnt lgkmcnt(0)");                                          \
    MM(1, 0);                                                                      \
    ENDW;                                                                          \
    __builtin_amdgcn_s_barrier();                                                  \
  } while (0)

  constexpr int NT = Nc / 64;   // 32 K-tiles
  // prologue: tile0 {A0,B1,A1,B0} + tile1 {A0,B1,A1}; stream order matches loop
  STAGE(As, 0, 0, A,  n0,       0);
  STAGE(Bs, 0, 1, Bg, m0 + 128, 0);
  STAGE(As, 0, 1, A,  n0 + 128, 0);
  STAGE(Bs, 0, 0, Bg, m0,       0);
  asm volatile("s_waitcnt vmcnt(4)" ::: "memory");
  STAGE(As, 1, 0, A,  n0,       64);
  STAGE(Bs, 1, 1, Bg, m0 + 128, 64);
  STAGE(As, 1, 1, A,  n0 + 128, 64);
  asm volatile("s_waitcnt vmcnt(6)" ::: "memory");
  __builtin_amdgcn_s_barrier();

  for (int t = 0; t < NT - 2; t += 2) {
    TILE(0, 1, t,     true, true, asm volatile("s_waitcnt vmcnt(6)" ::: "memory"));
    TILE(1, 0, t + 1, true, true, asm volatile("s_waitcnt vmcnt(6)" ::: "memory"));
  }
  TILE(0, 1, NT - 2, true,  false, asm volatile("s_waitcnt vmcnt(0)" ::: "memory"));
  TILE(1, 0, NT - 1, false, false, (void)0);

#undef TILE
#undef MM
#undef LDB
#undef LDA
#undef STAGE

  float* Sp = S + (size_t)b * Nc * Nc;
#pragma unroll
  for (int qm = 0; qm < 2; ++qm)
#pragma unroll
    for (int mi = 0; mi < 4; ++mi)
#pragma unroll
      for (int r = 0; r < 4; ++r) {
        const int row = n0 + qm * 128 + wm * 64 + mi * 16 + quad * 4 + r;
#pragma unroll
        for (int qn = 0; qn < 2; ++qn)
#pragma unroll
          for (int ni = 0; ni < 2; ++ni)
            Sp[(size_t)row * Nc + (m0 + qn * 128 + wn * 32 + ni * 16 + l16)] =
                acc[qm][mi][qn][ni][r];
      }
}

// ---------- Softmax over axis 1 (columns), in-place on S ----------
__global__ __launch_bounds__(256) void kS1(const float* __restrict__ S,
                                           float* __restrict__ pmax,
                                           float* __restrict__ psum) {
  const int b = blockIdx.z, mt = blockIdx.y, nc = blockIdx.x;
  const int m = mt * 256 + threadIdx.x;
  const float* col = S + (size_t)b * Nc * Nc + m;
  float mx = -3.0e38f, sm = 0.f;
  const int ns = nc * 512;
#pragma unroll 4
  for (int n = ns; n < ns + 512; ++n) {
    float v = col[(size_t)n * Nc];
    float nm = fmaxf(mx, v);
    sm = sm * __expf(mx - nm) + __expf(v - nm);
    mx = nm;
  }
  pmax[(size_t)(b * 4 + nc) * Nc + m] = mx;
  psum[(size_t)(b * 4 + nc) * Nc + m] = sm;
}

__global__ __launch_bounds__(256) void kS1b(const float* __restrict__ pmax,
                                            const float* __restrict__ psum,
                                            float* __restrict__ rmax,
                                            float* __restrict__ rinv) {
  const int i = blockIdx.x * 256 + threadIdx.x;   // b*Nc + m
  const int b = i >> 11, m = i & 2047;
  const float* pm = pmax + (size_t)b * 4 * Nc + m;
  const float* ps = psum + (size_t)b * 4 * Nc + m;
  float gm = pm[0];
#pragma unroll
  for (int c = 1; c < 4; ++c) gm = fmaxf(gm, pm[(size_t)c * Nc]);
  float gs = 0.f;
#pragma unroll
  for (int c = 0; c < 4; ++c) gs += ps[(size_t)c * Nc] * __expf(pm[(size_t)c * Nc] - gm);
  rmax[i] = gm;
  rinv[i] = 1.0f / gs;
}

__global__ __launch_bounds__(256) void kS2(float* __restrict__ S,
                                           const float* __restrict__ rmax,
                                           const float* __restrict__ rinv) {
  const int b = blockIdx.z, mt = blockIdx.y, nc = blockIdx.x;
  const int m = mt * 256 + threadIdx.x;
  const float gm = rmax[b * Nc + m];
  const float iv = rinv[b * Nc + m];
  float* col = S + (size_t)b * Nc * Nc + m;
  const int ns = nc * 256;
#pragma unroll 4
  for (int n = ns; n < ns + 256; ++n) {
    float v = col[(size_t)n * Nc];
    col[(size_t)n * Nc] = __expf(v - gm) * iv;
  }
}

// ---------- launch ----------
extern "C" void kernel_launch(void* const* d_in, const int* in_sizes, int n_in,
                              void* d_out, int out_size, void* d_ws, size_t ws_size,
                              hipStream_t stream) {
  const float* x   = (const float*)d_in[0];
  const float* W1  = (const float*)d_in[1];
  const float* W2  = (const float*)d_in[2];
  const float* W3  = (const float*)d_in[3];
  const float* bsr = (const float*)d_in[4];
  const float* Vs  = (const float*)d_in[5];
  float* out = (float*)d_out;

  // workspace layout (total 292,028,416 B)
  char* ws = (char*)d_ws;
  constexpr size_t SIGT_B = (size_t)Bc * Nc * Nc * 2;     // 268,435,456
  constexpr size_t VB_B   = (size_t)Nc * Nc * 2;          //   8,388,608
  constexpr size_t LHS_B  = (size_t)Bc * Nc * Tc * 4;     //   6,291,456
  constexpr size_t PM_B   = (size_t)Bc * 4 * Nc * 4;      //   1,048,576
  unsigned short* sigT = (unsigned short*)ws;
  unsigned short* Vb   = (unsigned short*)(ws + SIGT_B);
  float* lhs  = (float*)(ws + SIGT_B + VB_B);
  float* rhsT = (float*)(ws + SIGT_B + VB_B + LHS_B);
  float* pmax = (float*)(ws + SIGT_B + VB_B + 2 * LHS_B);
  float* psum = (float*)(ws + SIGT_B + VB_B + 2 * LHS_B + PM_B);
  float* rmax = (float*)(ws + SIGT_B + VB_B + 2 * LHS_B + 2 * PM_B);
  float* rinv = (float*)(ws + SIGT_B + VB_B + 2 * LHS_B + 2 * PM_B + (size_t)Bc * Nc * 4);

  kA<<<Bc * Nc / 4, 256, 0, stream>>>(x, W1, W2, W3, lhs, rhsT);
  kVs<<<(Nc * Nc) / 1024, 256, 0, stream>>>(Vs, Vb);
  kP<<<dim3(Nc / 128, Nc / 128, Bc), 256, 0, stream>>>(lhs, rhsT, bsr, sigT);
  kG<<<dim3((Nc / 256) * (Nc / 256), Bc), 512, 0, stream>>>(Vb, sigT, out);
  kS1<<<dim3(4, Nc / 256, Bc), 256, 0, stream>>>(out, pmax, psum);
  kS1b<<<Bc * Nc / 256, 256, 0, stream>>>(pmax, psum, rmax, rinv);
  kS2<<<dim3(Nc / 256, Nc / 256, Bc), 256, 0, stream>>>(out, rmax, rinv);
}

// Round 2
// 1770.764 us; speedup vs baseline: 1.2398x; 1.0611x over previous
//
#include <hip/hip_runtime.h>

// Problem constants
constexpr int Bc = 32, Nc = 2048, Fc = 64, Tc = 24;

// ---------- helpers ----------
__device__ __forceinline__ unsigned short f2bf(float f) {
  unsigned u = __float_as_uint(f);
  u += 0x7fffu + ((u >> 16) & 1u);   // round-to-nearest-even
  return (unsigned short)(u >> 16);
}

#define AS1(p) ((const __attribute__((address_space(1))) unsigned int*)(p))
#define AS3(p) ((__attribute__((address_space(3))) unsigned int*)(p))

typedef __attribute__((ext_vector_type(8))) short bfrag;   // 8 bf16 (4 VGPRs)
typedef __attribute__((ext_vector_type(4))) float ffrag;   // 4 fp32 acc

// ---------- Kernel A: x -> lhs[b,n,t], rhsT[b,m,t] ----------
__global__ __launch_bounds__(256) void kA(const float* __restrict__ x,
                                          const float* __restrict__ W1,
                                          const float* __restrict__ W2,
                                          const float* __restrict__ W3,
                                          float* __restrict__ lhs,
                                          float* __restrict__ rhsT) {
  __shared__ float W2s[Fc * Tc];      // 64x24
  __shared__ float xs[4][Fc][26];     // pad 24->26: breaks stride-24 bank aliasing
  __shared__ float tmp[4][Fc];
  const int tid = threadIdx.x;
  for (int i = tid; i < Fc * Tc; i += 256) W2s[i] = W2[i];
  const int wave = tid >> 6, lane = tid & 63;
  const size_t pair = (size_t)blockIdx.x * 4 + wave;   // pair = b*N + n
  const float* xp = x + pair * (size_t)(Fc * Tc);
#pragma unroll
  for (int s = 0; s < 12; ++s) {
    int f2 = lane + 64 * s;           // 0..767
    int row = f2 / 12, c2 = (f2 % 12) * 2;
    float2 v = *(const float2*)(xp + (size_t)f2 * 2);
    xs[wave][row][c2] = v.x;
    xs[wave][row][c2 + 1] = v.y;
  }
  __syncthreads();
  {
    const int f = lane;
    float acc = 0.f;
#pragma unroll
    for (int t = 0; t < Tc; ++t) acc += xs[wave][f][t] * W1[t];
    tmp[wave][f] = acc;
  }
  __syncthreads();
  if (lane < 48) {
    const int t = lane >> 1, h = lane & 1;
    const int f0 = h * 32;
    float lacc = 0.f, racc = 0.f;
#pragma unroll
    for (int i = 0; i < 32; ++i) {
      int f = f0 + i;
      lacc += tmp[wave][f] * W2s[f * Tc + t];
      racc += W3[f] * xs[wave][f][t];
    }
    lacc += __shfl_xor(lacc, 1);
    racc += __shfl_xor(racc, 1);
    if (h == 0) {
      lhs[pair * Tc + t] = lacc;
      rhsT[pair * Tc + t] = racc;
    }
  }
}

// ---------- Kernel V: Vs fp32 -> bf16 ----------
__global__ __launch_bounds__(256) void kVs(const float* __restrict__ Vs,
                                           unsigned short* __restrict__ Vb) {
  size_t i = ((size_t)blockIdx.x * 256 + threadIdx.x) * 4;
  float4 v = *(const float4*)(Vs + i);
  ushort4 o;
  o.x = f2bf(v.x); o.y = f2bf(v.y); o.z = f2bf(v.z); o.w = f2bf(v.w);
  *(ushort4*)(Vb + i) = o;
}

// ---------- Kernel P: sigT[b][m][k] = sigmoid(lhs[b,k,:].rhsT[b,m,:] + bs[k,m]) ----------
__global__ __launch_bounds__(256) void kP(const float* __restrict__ lhs,
                                          const float* __restrict__ rhsT,
                                          const float* __restrict__ bsr,
                                          unsigned short* __restrict__ sigT) {
  __shared__ float Lt[Tc][132];
  __shared__ float Rt[Tc][132];
  const int b = blockIdx.z;
  const int i0 = blockIdx.y * 128;
  const int j0 = blockIdx.x * 128;
  const int tid = threadIdx.x;
  const float* lp = lhs + ((size_t)b * Nc + i0) * Tc;
  const float* rp = rhsT + ((size_t)b * Nc + j0) * Tc;
#pragma unroll
  for (int s = 0; s < 6; ++s) {
    int f2 = tid + 256 * s;                 // 0..1535
    int row = f2 / 12, c2 = (f2 % 12) * 2;
    float2 v = *(const float2*)(lp + (size_t)row * Tc + c2);
    Lt[c2][row] = v.x; Lt[c2 + 1][row] = v.y;
    float2 w = *(const float2*)(rp + (size_t)row * Tc + c2);
    Rt[c2][row] = w.x; Rt[c2 + 1][row] = w.y;
  }
  __syncthreads();
  const int tx = tid & 15, ty = tid >> 4;
  const int ri = ty * 8, cj = tx * 8;
  float acc[8][8];
#pragma unroll
  for (int a = 0; a < 8; ++a) {   // init with bs tile
    const float* bp = bsr + (size_t)(i0 + ri + a) * Nc + j0 + cj;
    float4 b0 = *(const float4*)bp;
    float4 b1 = *(const float4*)(bp + 4);
    acc[a][0] = b0.x; acc[a][1] = b0.y; acc[a][2] = b0.z; acc[a][3] = b0.w;
    acc[a][4] = b1.x; acc[a][5] = b1.y; acc[a][6] = b1.z; acc[a][7] = b1.w;
  }
#pragma unroll
  for (int t = 0; t < Tc; ++t) {
    float la[8], ra[8];
    *(float4*)&la[0] = *(const float4*)&Lt[t][ri];
    *(float4*)&la[4] = *(const float4*)&Lt[t][ri + 4];
    *(float4*)&ra[0] = *(const float4*)&Rt[t][cj];
    *(float4*)&ra[4] = *(const float4*)&Rt[t][cj + 4];
#pragma unroll
    for (int a = 0; a < 8; ++a)
#pragma unroll
      for (int c = 0; c < 8; ++c) acc[a][c] += la[a] * ra[c];
  }
#pragma unroll
  for (int c = 0; c < 8; ++c) {
    unsigned short o[8];
#pragma unroll
    for (int a = 0; a < 8; ++a) {
      float e = __expf(-acc[a][c]);
      o[a] = f2bf(__fdividef(1.0f, 1.0f + e));
    }
    uint4 pk;
    pk.x = (unsigned)o[0] | ((unsigned)o[1] << 16);
    pk.y = (unsigned)o[2] | ((unsigned)o[3] << 16);
    pk.z = (unsigned)o[4] | ((unsigned)o[5] << 16);
    pk.w = (unsigned)o[6] | ((unsigned)o[7] << 16);
    *(uint4*)(sigT + ((size_t)b * Nc + j0 + cj + c) * Nc + i0 + ri) = pk;
  }
}

// ---------- Kernel G: S[b] = Vs_bf16 (N,N) @ sig_bf16[b] (N,N), fp32 out ----------
// 256x256 tile, BK=64, 8 waves, 8-phase schedule (T1+T2+T3+T4+T5).
// R2 change: swizzle upgraded from 1-bit st_16x32 to the 3-bit Guideline-4 form
//   byte ^= ((row&7)<<4)  i.e.  d ^= ((d>>7)&7)<<4   (row stride = 128 B).
// Rationale: ds_read addr = row*128 + ks*64 + quad*16 puts all 16 lanes of a quad in
// one 16B bank-slot (8-way conflict per phase group). XOR-ing row bits [2:0] into slot
// bits [6:4] makes each consecutive-8-lane group cover all 8 slots (residual 2-way is
// free, m136). Touches only bits [6:4] -> 16B-granular (global_load_lds compatible),
// involution (bits [9:7] unmodified). Same involution on stage-source and ds_read.
__global__ __launch_bounds__(512, 2) void kG(const unsigned short* __restrict__ A,
                                             const unsigned short* __restrict__ Bm,
                                             float* __restrict__ S) {
  __shared__ unsigned short As[2][2][8192];   // [buf][M-half][128x64]
  __shared__ unsigned short Bs[2][2][8192];   // [buf][N-half][128x64]
  const int b = blockIdx.y;
  const int bid = blockIdx.x;
  const int swz = (bid & 7) * 8 + (bid >> 3);   // XCD swizzle, bijective (64 % 8 == 0)
  const int n0 = (swz >> 3) << 8;
  const int m0 = (swz & 7) << 8;
  const int tid = threadIdx.x;
  const int wid = tid >> 6, lane = tid & 63;
  const int wm = wid >> 2, wn = wid & 3;        // 2 x 4 waves
  const int quad = lane >> 4, l16 = lane & 15;
  const unsigned short* Bg = Bm + (size_t)b * Nc * Nc;

  // staging source offsets: LDS dest is linear (base + lane*16); global source is
  // the inverse-swizzled address so that swizzled ds_read returns correct data.
  int srow[2], scol[2], sbase[2];
#pragma unroll
  for (int c = 0; c < 2; ++c) {
    const int d = c * 8192 + (wid << 10) + (lane << 4);   // dest byte in 16 KiB half
    const int q = d ^ (((d >> 7) & 7) << 4);              // 3-bit row-XOR involution
    srow[c] = q >> 7;            // logical row (0..127)
    scol[c] = (q & 127) >> 1;    // logical col element (0..63)
    sbase[c] = (c * 8192 + (wid << 10)) >> 1;             // wave-uniform LDS short idx
  }

#define STAGE(arr, bufb, half, gb, ro, k0)                                         \
  do {                                                                             \
    _Pragma("unroll")                                                              \
    for (int c = 0; c < 2; ++c)                                                    \
      __builtin_amdgcn_global_load_lds(                                            \
          AS1(gb + (size_t)((ro) + srow[c]) * Nc + (k0) + scol[c]),                \
          AS3(&arr[bufb][half][0] + sbase[c]), 16, 0, 0);                          \
  } while (0)

  ffrag acc[2][4][2][2];
#pragma unroll
  for (int qm = 0; qm < 2; ++qm)
#pragma unroll
    for (int mi = 0; mi < 4; ++mi)
#pragma unroll
      for (int qn = 0; qn < 2; ++qn)
#pragma unroll
        for (int ni = 0; ni < 2; ++ni) acc[qm][mi][qn][ni] = (ffrag){0.f, 0.f, 0.f, 0.f};

  bfrag af[4][2], bfr[2][2];

#define LDA(qm, bufb)                                                              \
  do {                                                                             \
    _Pragma("unroll")                                                              \
    for (int mi = 0; mi < 4; ++mi)                                                 \
      _Pragma("unroll")                                                            \
      for (int ks = 0; ks < 2; ++ks) {                                             \
        const int lin = (wm * 64 + mi * 16 + l16) * 128 + ks * 64 + quad * 16;     \
        const int ph = lin ^ (((lin >> 7) & 7) << 4);                              \
        af[mi][ks] = *(const bfrag*)((const char*)&As[bufb][qm][0] + ph);          \
      }                                                                            \
  } while (0)

#define LDB(qn, bufb)                                                              \
  do {                                                                             \
    _Pragma("unroll")                                                              \
    for (int ni = 0; ni < 2; ++ni)                                                 \
      _Pragma("unroll")                                                            \
      for (int ks = 0; ks < 2; ++ks) {                                             \
        const int lin = (wn * 32 + ni * 16 + l16) * 128 + ks * 64 + quad * 16;     \
        const int ph = lin ^ (((lin >> 7) & 7) << 4);                              \
        bfr[ni][ks] = *(const bfrag*)((const char*)&Bs[bufb][qn][0] + ph);         \
      }                                                                            \
  } while (0)

#define MM(qm, qn)                                                                 \
  do {                                                                             \
    __builtin_amdgcn_s_setprio(1);                                                 \
    _Pragma("unroll")                                                              \
    for (int mi = 0; mi < 4; ++mi)                                                 \
      _Pragma("unroll")                                                            \
      for (int ni = 0; ni < 2; ++ni)                                               \
        _Pragma("unroll")                                                          \
        for (int ks = 0; ks < 2; ++ks)                                             \
          acc[qm][mi][qn][ni] = __builtin_amdgcn_mfma_f32_16x16x32_bf16(           \
              af[mi][ks], bfr[ni][ks], acc[qm][mi][qn][ni], 0, 0, 0);              \
    __builtin_amdgcn_s_setprio(0);                                                 \
  } while (0)

#define TILE(BUF, OT, T, DO_S1, DO_S2, ENDW)                                       \
  do {                                                                             \
    const int k1 = ((T) + 1) << 6, k2 = ((T) + 2) << 6;                            \
    /* phase 0: quadrant (0,0) */                                                  \
    LDA(0, BUF); LDB(0, BUF);                                                      \
    if (DO_S1) STAGE(Bs, OT, 0, Bg, m0, k1);                                       \
    asm volatile("s_waitcnt lgkmcnt(8)");                                          \
    __builtin_amdgcn_s_barrier();                                                  \
    asm volatile("s_waitcnt lgkmcnt(0)");                                          \
    MM(0, 0);                                                                      \
    __builtin_amdgcn_s_barrier();                                                  \
    /* phase 1: quadrant (0,1) — A-frags reused */                                 \
    LDB(1, BUF);                                                                   \
    if (DO_S2) STAGE(As, BUF, 0, A, n0, k2);                                       \
    __builtin_amdgcn_s_barrier();                                                  \
    asm volatile("s_waitcnt lgkmcnt(0)");                                          \
    MM(0, 1);                                                                      \
    __builtin_amdgcn_s_barrier();                                                  \
    /* phase 2: quadrant (1,1) — B-frags reused */                                 \
    LDA(1, BUF);                                                                   \
    if (DO_S2) STAGE(Bs, BUF, 1, Bg, m0 + 128, k2);                                \
    __builtin_amdgcn_s_barrier();                                                  \
    asm volatile("s_waitcnt lgkmcnt(0)");                                          \
    MM(1, 1);                                                                      \
    __builtin_amdgcn_s_barrier();                                                  \
    /* phase 3: quadrant (1,0) */                                                  \
    LDB(0, BUF);                                                                   \
    if (DO_S2) STAGE(As, BUF, 1, A, n0 + 128, k2);                                 \
    __builtin_amdgcn_s_barrier();                                                  \
    asm volatile("s_waitcnt lgkmcnt(0)");                                          \
    MM(1, 0);                                                                      \
    ENDW;                                                                          \
    __builtin_amdgcn_s_barrier();                                                  \
  } while (0)

  constexpr int NT = Nc / 64;   // 32 K-tiles
  // prologue: tile0 {A0,B1,A1,B0} + tile1 {A0,B1,A1}; stream order matches loop
  STAGE(As, 0, 0, A,  n0,       0);
  STAGE(Bs, 0, 1, Bg, m0 + 128, 0);
  STAGE(As, 0, 1, A,  n0 + 128, 0);
  STAGE(Bs, 0, 0, Bg, m0,       0);
  asm volatile("s_waitcnt vmcnt(4)" ::: "memory");
  STAGE(As, 1, 0, A,  n0,       64);
  STAGE(Bs, 1, 1, Bg, m0 + 128, 64);
  STAGE(As, 1, 1, A,  n0 + 128, 64);
  asm volatile("s_waitcnt vmcnt(6)" ::: "memory");
  __builtin_amdgcn_s_barrier();

  for (int t = 0; t < NT - 2; t += 2) {
    TILE(0, 1, t,     true, true, asm volatile("s_waitcnt vmcnt(6)" ::: "memory"));
    TILE(1, 0, t + 1, true, true, asm volatile("s_waitcnt vmcnt(6)" ::: "memory"));
  }
  TILE(0, 1, NT - 2, true,  false, asm volatile("s_waitcnt vmcnt(0)" ::: "memory"));
  TILE(1, 0, NT - 1, false, false, (void)0);

#undef TILE
#undef MM
#undef LDB
#undef LDA
#undef STAGE

  float* Sp = S + (size_t)b * Nc * Nc;
#pragma unroll
  for (int qm = 0; qm < 2; ++qm)
#pragma unroll
    for (int mi = 0; mi < 4; ++mi)
#pragma unroll
      for (int r = 0; r < 4; ++r) {
        const int row = n0 + qm * 128 + wm * 64 + mi * 16 + quad * 4 + r;
#pragma unroll
        for (int qn = 0; qn < 2; ++qn)
#pragma unroll
          for (int ni = 0; ni < 2; ++ni)
            Sp[(size_t)row * Nc + (m0 + qn * 128 + wn * 32 + ni * 16 + l16)] =
                acc[qm][mi][qn][ni][r];
      }
}

// ---------- Softmax over axis 1 (columns), in-place on S ----------
__global__ __launch_bounds__(256) void kS1(const float* __restrict__ S,
                                           float* __restrict__ pmax,
                                           float* __restrict__ psum) {
  const int b = blockIdx.z, mt = blockIdx.y, nc = blockIdx.x;
  const int m = mt * 256 + threadIdx.x;
  const float* col = S + (size_t)b * Nc * Nc + m;
  float mx = -3.0e38f, sm = 0.f;
  const int ns = nc * 512;
#pragma unroll 4
  for (int n = ns; n < ns + 512; ++n) {
    float v = col[(size_t)n * Nc];
    float nm = fmaxf(mx, v);
    sm = sm * __expf(mx - nm) + __expf(v - nm);
    mx = nm;
  }
  pmax[(size_t)(b * 4 + nc) * Nc + m] = mx;
  psum[(size_t)(b * 4 + nc) * Nc + m] = sm;
}

__global__ __launch_bounds__(256) void kS1b(const float* __restrict__ pmax,
                                            const float* __restrict__ psum,
                                            float* __restrict__ rmax,
                                            float* __restrict__ rinv) {
  const int i = blockIdx.x * 256 + threadIdx.x;   // b*Nc + m
  const int b = i >> 11, m = i & 2047;
  const float* pm = pmax + (size_t)b * 4 * Nc + m;
  const float* ps = psum + (size_t)b * 4 * Nc + m;
  float gm = pm[0];
#pragma unroll
  for (int c = 1; c < 4; ++c) gm = fmaxf(gm, pm[(size_t)c * Nc]);
  float gs = 0.f;
#pragma unroll
  for (int c = 0; c < 4; ++c) gs += ps[(size_t)c * Nc] * __expf(pm[(size_t)c * Nc] - gm);
  rmax[i] = gm;
  rinv[i] = 1.0f / gs;
}

__global__ __launch_bounds__(256) void kS2(float* __restrict__ S,
                                           const float* __restrict__ rmax,
                                           const float* __restrict__ rinv) {
  const int b = blockIdx.z, mt = blockIdx.y, nc = blockIdx.x;
  const int m = mt * 256 + threadIdx.x;
  const float gm = rmax[b * Nc + m];
  const float iv = rinv[b * Nc + m];
  float* col = S + (size_t)b * Nc * Nc + m;
  const int ns = nc * 256;
#pragma unroll 4
  for (int n = ns; n < ns + 256; ++n) {
    float v = col[(size_t)n * Nc];
    col[(size_t)n * Nc] = __expf(v - gm) * iv;
  }
}

// ---------- launch ----------
extern "C" void kernel_launch(void* const* d_in, const int* in_sizes, int n_in,
                              void* d_out, int out_size, void* d_ws, size_t ws_size,
                              hipStream_t stream) {
  const float* x   = (const float*)d_in[0];
  const float* W1  = (const float*)d_in[1];
  const float* W2  = (const float*)d_in[2];
  const float* W3  = (const float*)d_in[3];
  const float* bsr = (const float*)d_in[4];
  const float* Vs  = (const float*)d_in[5];
  float* out = (float*)d_out;

  // workspace layout (total 292,028,416 B)
  char* ws = (char*)d_ws;
  constexpr size_t SIGT_B = (size_t)Bc * Nc * Nc * 2;     // 268,435,456
  constexpr size_t VB_B   = (size_t)Nc * Nc * 2;          //   8,388,608
  constexpr size_t LHS_B  = (size_t)Bc * Nc * Tc * 4;     //   6,291,456
  constexpr size_t PM_B   = (size_t)Bc * 4 * Nc * 4;      //   1,048,576
  unsigned short* sigT = (unsigned short*)ws;
  unsigned short* Vb   = (unsigned short*)(ws + SIGT_B);
  float* lhs  = (float*)(ws + SIGT_B + VB_B);
  float* rhsT = (float*)(ws + SIGT_B + VB_B + LHS_B);
  float* pmax = (float*)(ws + SIGT_B + VB_B + 2 * LHS_B);
  float* psum = (float*)(ws + SIGT_B + VB_B + 2 * LHS_B + PM_B);
  float* rmax = (float*)(ws + SIGT_B + VB_B + 2 * LHS_B + 2 * PM_B);
  float* rinv = (float*)(ws + SIGT_B + VB_B + 2 * LHS_B + 2 * PM_B + (size_t)Bc * Nc * 4);

  kA<<<Bc * Nc / 4, 256, 0, stream>>>(x, W1, W2, W3, lhs, rhsT);
  kVs<<<(Nc * Nc) / 1024, 256, 0, stream>>>(Vs, Vb);
  kP<<<dim3(Nc / 128, Nc / 128, Bc), 256, 0, stream>>>(lhs, rhsT, bsr, sigT);
  kG<<<dim3((Nc / 256) * (Nc / 256), Bc), 512, 0, stream>>>(Vb, sigT, out);
  kS1<<<dim3(4, Nc / 256, Bc), 256, 0, stream>>>(out, pmax, psum);
  kS1b<<<Bc * Nc / 256, 256, 0, stream>>>(pmax, psum, rmax, rinv);
  kS2<<<dim3(Nc / 256, Nc / 256, Bc), 256, 0, stream>>>(out, rmax, rinv);
}